// Round 2
// baseline (120.964 us; speedup 1.0000x reference)
//
#include <hip/hip_runtime.h>
#include <hip/hip_bf16.h>
#include <stdint.h>

#define BATCH 32
#define CIN   256
#define COUT  256
#define HW    3136   // 56*56
#define NPAD  3200   // pad HW to multiple of 128

typedef short bf16x8 __attribute__((ext_vector_type(8)));
typedef float f32x4  __attribute__((ext_vector_type(4)));

__device__ __forceinline__ unsigned short f2bf(float f) {
    unsigned u = __float_as_uint(f);
    u += 0x7fffu + ((u >> 16) & 1u);   // round-to-nearest-even
    return (unsigned short)(u >> 16);
}

// ---------------- K0: fold BN2 into pointwise weights, zero pwmax ----------
__global__ __launch_bounds__(256) void prep_kernel(
        const float* __restrict__ pw_w, const float* __restrict__ pw_b,
        const float* __restrict__ g2, const float* __restrict__ be2,
        const float* __restrict__ mu2, const float* __restrict__ va2,
        unsigned short* __restrict__ Wp, float* __restrict__ b2,
        unsigned* __restrict__ pwmax) {
    int o = blockIdx.x;
    int t = threadIdx.x;
    float inv2 = g2[o] * rsqrtf(va2[o] + 1e-5f);
    Wp[o * CIN + t] = f2bf(pw_w[o * CIN + t] * inv2);
    if (t == 0) b2[o] = pw_b[o] * inv2 + be2[o] - mu2[o] * inv2;
    int idx = blockIdx.x * 256 + t;
    if (idx < BATCH * COUT) pwmax[idx] = 0u;
}

// ---------------- K1: depthwise 3x3 + BN1 + ReLU + plane cut -> y bf16 -----
// One block per (b,c) plane. No LDS: plane is 12.5 KB, L1-resident.
// Each thread computes quads of 4 horizontally-adjacent pixels.
__global__ __launch_bounds__(256) void dw_kernel(
        const float* __restrict__ x, const float* __restrict__ dww,
        const float* __restrict__ dwb,
        const float* __restrict__ g1, const float* __restrict__ be1,
        const float* __restrict__ mu1, const float* __restrict__ va1,
        unsigned short* __restrict__ y) {
    int blk = blockIdx.x;
    int c = blk & 255;
    int b = blk >> 8;
    int tid = threadIdx.x;
    const float* xp = x + (size_t)(b * CIN + c) * HW;

    float w00 = dww[c*9+0], w01 = dww[c*9+1], w02 = dww[c*9+2];
    float w10 = dww[c*9+3], w11 = dww[c*9+4], w12 = dww[c*9+5];
    float w20 = dww[c*9+6], w21 = dww[c*9+7], w22 = dww[c*9+8];
    float inv = g1[c] * rsqrtf(va1[c] + 1e-5f);
    float b0  = dwb[c] * inv + (be1[c] - mu1[c] * inv);

    float vals[4][4];
    float lmax = 0.f;
#pragma unroll
    for (int i = 0; i < 4; ++i) {
        int q = tid + i * 256;          // quad index, 784 total
        int qq = q < 784 ? q : 783;
        int h = qq / 14;                // output row
        int c0 = (qq - h * 14) * 4;     // output col base (0..52)
        float a0 = 0.f, a1 = 0.f, a2 = 0.f, a3 = 0.f;
#pragma unroll
        for (int r = 0; r < 3; ++r) {
            int gr = h + r - 1;
            bool rv = (unsigned)gr < 56u;
            int grc = gr < 0 ? 0 : (gr > 55 ? 55 : gr);
            const float* rowp = xp + grc * 56;
            float4 vv = *(const float4*)(rowp + c0);      // aligned, in-bounds
            float s0 = (rv && c0 != 0) ? rowp[c0 - 1] : 0.f;
            float s5 = (rv && c0 < 52) ? rowp[c0 + 4] : 0.f;
            float s1 = rv ? vv.x : 0.f;
            float s2 = rv ? vv.y : 0.f;
            float s3 = rv ? vv.z : 0.f;
            float s4 = rv ? vv.w : 0.f;
            float wl = r == 0 ? w00 : (r == 1 ? w10 : w20);
            float wc = r == 0 ? w01 : (r == 1 ? w11 : w21);
            float wr = r == 0 ? w02 : (r == 1 ? w12 : w22);
            a0 = fmaf(s0, wl, fmaf(s1, wc, fmaf(s2, wr, a0)));
            a1 = fmaf(s1, wl, fmaf(s2, wc, fmaf(s3, wr, a1)));
            a2 = fmaf(s2, wl, fmaf(s3, wc, fmaf(s4, wr, a2)));
            a3 = fmaf(s3, wl, fmaf(s4, wc, fmaf(s5, wr, a3)));
        }
        float v0 = fmaxf(fmaf(a0, inv, b0), 0.f);
        float v1 = fmaxf(fmaf(a1, inv, b0), 0.f);
        float v2 = fmaxf(fmaf(a2, inv, b0), 0.f);
        float v3 = fmaxf(fmaf(a3, inv, b0), 0.f);
        vals[i][0] = v0; vals[i][1] = v1; vals[i][2] = v2; vals[i][3] = v3;
        if (q < 784)
            lmax = fmaxf(lmax, fmaxf(fmaxf(v0, v1), fmaxf(v2, v3)));
    }

    __shared__ float red[4];
    __shared__ float bmax_sh;
    for (int off = 32; off >= 1; off >>= 1)
        lmax = fmaxf(lmax, __shfl_xor(lmax, off, 64));
    if ((tid & 63) == 0) red[tid >> 6] = lmax;
    __syncthreads();
    if (tid == 0) bmax_sh = fmaxf(fmaxf(red[0], red[1]), fmaxf(red[2], red[3]));
    __syncthreads();
    bool cut = (bmax_sh < 4.0f);

    unsigned short* yp = y + (size_t)(b * CIN + c) * NPAD;
    ushort4 zero4 = make_ushort4(0, 0, 0, 0);
#pragma unroll
    for (int i = 0; i < 4; ++i) {
        int q = tid + i * 256;
        if (q < 784) {
            ushort4 o = zero4;
            if (!cut) {
                o.x = f2bf(vals[i][0]); o.y = f2bf(vals[i][1]);
                o.z = f2bf(vals[i][2]); o.w = f2bf(vals[i][3]);
            }
            *(ushort4*)(yp + q * 4) = o;
        }
    }
    if (tid < 16) *(ushort4*)(yp + HW + tid * 4) = zero4;  // pad cols
}

// ---------------- K2: pointwise GEMM (bf16 MFMA) + BN2 + ReLU + row max ----
// Z_b (O x HW) = W' (O x C) * Y_b (C x HW)
// T14 structure: prefetch next K-step to regs before barrier; raw s_barrier +
// manual lgkmcnt-only waits keep global loads in flight across barriers.
__global__ __launch_bounds__(256) void pw_kernel(
        const unsigned short* __restrict__ y, const unsigned short* __restrict__ Wp,
        const float* __restrict__ b2, float* __restrict__ z,
        unsigned* __restrict__ pwmax) {
    __shared__ __align__(16) unsigned short Al[128 * 64];  // [m][k], chunk-swizzled by (m&7)
    __shared__ __align__(16) unsigned short Bl[128 * 64];  // [n][k], chunk-swizzled by ((n>>2)&7)

    int bid = blockIdx.x;
    int mt = bid & 1;
    int rest = bid >> 1;
    int nt = rest % 25;
    int b = rest / 25;
    int m0 = mt * 128, n0 = nt * 128;

    int tid = threadIdx.x;
    int lane = tid & 63, wid = tid >> 6;
    int wm = (wid & 1) * 64, wn = (wid >> 1) * 64;
    int l15 = lane & 15, l4 = lane >> 4;

    const unsigned short* yb = y + (size_t)b * CIN * NPAD;

    // per-thread staging maps
    int am[4], acch[4];
    const unsigned short* asrc[4];
#pragma unroll
    for (int i = 0; i < 4; ++i) {
        int s = i * 256 + tid;
        int m = s >> 3, cch = s & 7, dch = cch ^ (m & 7);
        am[i] = m; acch[i] = cch;
        asrc[i] = Wp + (size_t)(m0 + m) * CIN + dch * 8;
    }
    int bq[2], bnq[2];
    const unsigned short* bsrc[2];
#pragma unroll
    for (int i = 0; i < 2; ++i) {
        int u = tid + i * 256;
        bq[i] = u >> 5; bnq[i] = u & 31;
        bsrc[i] = yb + (size_t)(bq[i] * 4) * NPAD + n0 + bnq[i] * 4;
    }

    uint4 areg[4];
    uint2 breg[2][4];
#pragma unroll
    for (int i = 0; i < 4; ++i) areg[i] = *(const uint4*)(asrc[i]);
#pragma unroll
    for (int i = 0; i < 2; ++i)
#pragma unroll
        for (int r = 0; r < 4; ++r) breg[i][r] = *(const uint2*)(bsrc[i] + r * NPAD);

    f32x4 acc[4][4];
#pragma unroll
    for (int mf = 0; mf < 4; ++mf)
#pragma unroll
        for (int nf = 0; nf < 4; ++nf) acc[mf][nf] = {0.f, 0.f, 0.f, 0.f};

#pragma unroll
    for (int kk = 0; kk < 4; ++kk) {
        __builtin_amdgcn_s_barrier();      // all waves done reading LDS (iter 0: no-op)
        __builtin_amdgcn_sched_barrier(0);
        // A: store prefetched regs (swizzled slots)
#pragma unroll
        for (int i = 0; i < 4; ++i)
            *(uint4*)((char*)Al + am[i] * 128 + acch[i] * 16) = areg[i];
        // B: pack transpose from regs, store (swizzled)
#pragma unroll
        for (int i = 0; i < 2; ++i) {
            uint2 r0 = breg[i][0], r1 = breg[i][1], r2 = breg[i][2], r3 = breg[i][3];
            int q = bq[i], nq = bnq[i];
#pragma unroll
            for (int i2 = 0; i2 < 4; ++i2) {
                unsigned x0 = (i2 & 2) ? r0.y : r0.x;
                unsigned x1 = (i2 & 2) ? r1.y : r1.x;
                unsigned x2 = (i2 & 2) ? r2.y : r2.x;
                unsigned x3 = (i2 & 2) ? r3.y : r3.x;
                if (i2 & 1) { x0 >>= 16; x2 >>= 16; }
                else        { x0 &= 0xffffu; x2 &= 0xffffu; }
                unsigned px = (i2 & 1) ? (x0 | (x1 & 0xffff0000u))
                                       : (x0 | (x1 << 16));
                unsigned py = (i2 & 1) ? (x2 | (x3 & 0xffff0000u))
                                       : (x2 | (x3 << 16));
                int nloc = nq * 4 + i2;
                int sb = nloc * 128 + (((q >> 1) ^ ((nloc >> 2) & 7)) << 4) + ((q & 1) << 3);
                *(uint2*)((char*)Bl + sb) = make_uint2(px, py);
            }
        }
        // prefetch next K-step into regs (stays in flight across the barrier)
        if (kk < 3) {
#pragma unroll
            for (int i = 0; i < 4; ++i)
                areg[i] = *(const uint4*)(asrc[i] + (kk + 1) * 64);
#pragma unroll
            for (int i = 0; i < 2; ++i)
#pragma unroll
                for (int r = 0; r < 4; ++r)
                    breg[i][r] = *(const uint2*)(bsrc[i] + (size_t)(kk + 1) * 64 * NPAD + r * NPAD);
        }
        asm volatile("s_waitcnt lgkmcnt(0)" ::: "memory");  // LDS writes visible; vmcnt NOT drained
        __builtin_amdgcn_s_barrier();
        __builtin_amdgcn_sched_barrier(0);
        // compute this K-step: 2 halves of K=32
#pragma unroll
        for (int h = 0; h < 2; ++h) {
            bf16x8 af[4], bfr[4];
            int cc = h * 4 + l4;
#pragma unroll
            for (int mf = 0; mf < 4; ++mf) {
                int m = wm + mf * 16 + l15;
                af[mf] = *(const bf16x8*)((const char*)Al + m * 128 + ((cc ^ (m & 7)) << 4));
            }
#pragma unroll
            for (int nf = 0; nf < 4; ++nf) {
                int n = wn + nf * 16 + l15;
                bfr[nf] = *(const bf16x8*)((const char*)Bl + n * 128 + ((cc ^ ((n >> 2) & 7)) << 4));
            }
#pragma unroll
            for (int mf = 0; mf < 4; ++mf)
#pragma unroll
                for (int nf = 0; nf < 4; ++nf)
                    acc[mf][nf] = __builtin_amdgcn_mfma_f32_16x16x32_bf16(
                        af[mf], bfr[nf], acc[mf][nf], 0, 0, 0);
        }
    }

    // epilogue: bias + relu + store + per-o-row plane max (atomic)
    float* zb = z + (size_t)b * COUT * HW;
#pragma unroll
    for (int mf = 0; mf < 4; ++mf) {
        int obase = m0 + wm + mf * 16 + l4 * 4;
        float bb0 = b2[obase + 0], bb1 = b2[obase + 1];
        float bb2v = b2[obase + 2], bb3 = b2[obase + 3];
        float rmax[4] = {0.f, 0.f, 0.f, 0.f};
#pragma unroll
        for (int nf = 0; nf < 4; ++nf) {
            int n = n0 + wn + nf * 16 + l15;
            bool valid = (n < HW);
            float v0 = fmaxf(acc[mf][nf][0] + bb0, 0.f);
            float v1 = fmaxf(acc[mf][nf][1] + bb1, 0.f);
            float v2 = fmaxf(acc[mf][nf][2] + bb2v, 0.f);
            float v3 = fmaxf(acc[mf][nf][3] + bb3, 0.f);
            if (valid) {
                zb[(size_t)(obase + 0) * HW + n] = v0;
                zb[(size_t)(obase + 1) * HW + n] = v1;
                zb[(size_t)(obase + 2) * HW + n] = v2;
                zb[(size_t)(obase + 3) * HW + n] = v3;
                rmax[0] = fmaxf(rmax[0], v0);
                rmax[1] = fmaxf(rmax[1], v1);
                rmax[2] = fmaxf(rmax[2], v2);
                rmax[3] = fmaxf(rmax[3], v3);
            }
        }
#pragma unroll
        for (int r = 0; r < 4; ++r) {
            float v = rmax[r];
            v = fmaxf(v, __shfl_xor(v, 1, 64));
            v = fmaxf(v, __shfl_xor(v, 2, 64));
            v = fmaxf(v, __shfl_xor(v, 4, 64));
            v = fmaxf(v, __shfl_xor(v, 8, 64));
            if (l15 == 0)
                atomicMax(&pwmax[b * COUT + obase + r], __float_as_uint(v));
        }
    }
}

// ---------------- K3: apply pointwise cut ---------------------------------
__global__ __launch_bounds__(256) void cut_kernel(const unsigned* __restrict__ pwmax,
                                                  float* __restrict__ z) {
    int base = blockIdx.x * 8;
#pragma unroll
    for (int j = 0; j < 8; ++j) {
        int bo = base + j;
        if (__uint_as_float(pwmax[bo]) >= 1e-3f) continue;
        float4* zp = (float4*)(z + (size_t)bo * HW);
        for (int i = threadIdx.x; i < HW / 4; i += 256)
            zp[i] = make_float4(0.f, 0.f, 0.f, 0.f);
    }
}

extern "C" void kernel_launch(void* const* d_in, const int* in_sizes, int n_in,
                              void* d_out, int out_size, void* d_ws, size_t ws_size,
                              hipStream_t stream) {
    const float* x   = (const float*)d_in[0];
    const float* dww = (const float*)d_in[1];
    const float* dwb = (const float*)d_in[2];
    const float* g1  = (const float*)d_in[3];
    const float* be1 = (const float*)d_in[4];
    const float* mu1 = (const float*)d_in[5];
    const float* va1 = (const float*)d_in[6];
    const float* pww = (const float*)d_in[7];
    const float* pwb = (const float*)d_in[8];
    const float* g2  = (const float*)d_in[9];
    const float* be2 = (const float*)d_in[10];
    const float* mu2 = (const float*)d_in[11];
    const float* va2 = (const float*)d_in[12];
    float* z = (float*)d_out;

    char* ws = (char*)d_ws;
    const size_t Y_BYTES = (size_t)BATCH * CIN * NPAD * 2;  // 52,428,800
    unsigned short* y  = (unsigned short*)ws;
    unsigned short* Wp = (unsigned short*)(ws + Y_BYTES);
    float* b2          = (float*)(ws + Y_BYTES + 131072);
    unsigned* pwmax    = (unsigned*)(ws + Y_BYTES + 131072 + 1024);

    prep_kernel<<<256, 256, 0, stream>>>(pww, pwb, g2, be2, mu2, va2, Wp, b2, pwmax);
    dw_kernel<<<BATCH * CIN, 256, 0, stream>>>(x, dww, dwb, g1, be1, mu1, va1, y);
    pw_kernel<<<2 * 25 * BATCH, 256, 0, stream>>>(y, Wp, b2, z, pwmax);
    cut_kernel<<<BATCH * COUT / 8, 256, 0, stream>>>(pwmax, z);
}

// Round 3
// 120.394 us; speedup vs baseline: 1.0047x; 1.0047x over previous
//
#include <hip/hip_runtime.h>
#include <hip/hip_bf16.h>
#include <stdint.h>

#define BATCH 32
#define CIN   256
#define COUT  256
#define HW    3136   // 56*56
#define NPAD  3200   // pad HW to multiple of 128

typedef short bf16x8 __attribute__((ext_vector_type(8)));
typedef float f32x4  __attribute__((ext_vector_type(4)));

__device__ __forceinline__ unsigned short f2bf(float f) {
    unsigned u = __float_as_uint(f);
    u += 0x7fffu + ((u >> 16) & 1u);   // round-to-nearest-even
    return (unsigned short)(u >> 16);
}

// ---------------- K0: fold BN2 into pw weights; zero pwmax & dwmax ---------
__global__ __launch_bounds__(256) void prep_kernel(
        const float* __restrict__ pw_w, const float* __restrict__ pw_b,
        const float* __restrict__ g2, const float* __restrict__ be2,
        const float* __restrict__ mu2, const float* __restrict__ va2,
        unsigned short* __restrict__ Wp, float* __restrict__ b2,
        unsigned* __restrict__ pwmax, unsigned* __restrict__ dwmax) {
    int o = blockIdx.x;
    int t = threadIdx.x;
    float inv2 = g2[o] * rsqrtf(va2[o] + 1e-5f);
    Wp[o * CIN + t] = f2bf(pw_w[o * CIN + t] * inv2);
    if (t == 0) b2[o] = pw_b[o] * inv2 + be2[o] - mu2[o] * inv2;
    int idx = blockIdx.x * 256 + t;
    if (idx < BATCH * COUT) { pwmax[idx] = 0u; dwmax[idx] = 0u; }
}

// ---------------- K1: depthwise 3x3 + BN1 + ReLU -> y bf16 (UNCUT) --------
// One block per (b,c) plane. NO LDS, NO barriers: plane max goes to dwmax
// via wave shfl-reduce + one atomicMax per wave. Stores are unconditional,
// so loads/compute/stores pipeline freely within and across blocks.
__global__ __launch_bounds__(256) void dw_kernel(
        const float* __restrict__ x, const float* __restrict__ dww,
        const float* __restrict__ dwb,
        const float* __restrict__ g1, const float* __restrict__ be1,
        const float* __restrict__ mu1, const float* __restrict__ va1,
        unsigned short* __restrict__ y, unsigned* __restrict__ dwmax) {
    int blk = blockIdx.x;
    int c = blk & 255;
    int b = blk >> 8;
    int tid = threadIdx.x;
    const float* xp = x + (size_t)(b * CIN + c) * HW;

    float w00 = dww[c*9+0], w01 = dww[c*9+1], w02 = dww[c*9+2];
    float w10 = dww[c*9+3], w11 = dww[c*9+4], w12 = dww[c*9+5];
    float w20 = dww[c*9+6], w21 = dww[c*9+7], w22 = dww[c*9+8];
    float inv = g1[c] * rsqrtf(va1[c] + 1e-5f);
    float b0  = dwb[c] * inv + (be1[c] - mu1[c] * inv);

    float vals[4][4];
    float lmax = 0.f;
#pragma unroll
    for (int i = 0; i < 4; ++i) {
        int q = tid + i * 256;          // quad index, 784 total
        bool qv = (i < 3) || (tid < 16);
        int qq = qv ? q : 783;
        int h = qq / 14;                // output row
        int c0 = (qq - h * 14) * 4;     // output col base (0..52)
        float a0 = 0.f, a1 = 0.f, a2 = 0.f, a3 = 0.f;
#pragma unroll
        for (int r = 0; r < 3; ++r) {
            int gr = h + r - 1;
            bool rv = (unsigned)gr < 56u;
            int grc = gr < 0 ? 0 : (gr > 55 ? 55 : gr);
            const float* rowp = xp + grc * 56;
            float4 vv = *(const float4*)(rowp + c0);      // aligned, in-bounds
            float s0 = (rv && c0 != 0) ? rowp[c0 - 1] : 0.f;
            float s5 = (rv && c0 < 52) ? rowp[c0 + 4] : 0.f;
            float s1 = rv ? vv.x : 0.f;
            float s2 = rv ? vv.y : 0.f;
            float s3 = rv ? vv.z : 0.f;
            float s4 = rv ? vv.w : 0.f;
            float wl = r == 0 ? w00 : (r == 1 ? w10 : w20);
            float wc = r == 0 ? w01 : (r == 1 ? w11 : w21);
            float wr = r == 0 ? w02 : (r == 1 ? w12 : w22);
            a0 = fmaf(s0, wl, fmaf(s1, wc, fmaf(s2, wr, a0)));
            a1 = fmaf(s1, wl, fmaf(s2, wc, fmaf(s3, wr, a1)));
            a2 = fmaf(s2, wl, fmaf(s3, wc, fmaf(s4, wr, a2)));
            a3 = fmaf(s3, wl, fmaf(s4, wc, fmaf(s5, wr, a3)));
        }
        float v0 = fmaxf(fmaf(a0, inv, b0), 0.f);
        float v1 = fmaxf(fmaf(a1, inv, b0), 0.f);
        float v2 = fmaxf(fmaf(a2, inv, b0), 0.f);
        float v3 = fmaxf(fmaf(a3, inv, b0), 0.f);
        vals[i][0] = v0; vals[i][1] = v1; vals[i][2] = v2; vals[i][3] = v3;
        if (qv)
            lmax = fmaxf(lmax, fmaxf(fmaxf(v0, v1), fmaxf(v2, v3)));
    }

    // wave-level max reduce + one atomic per wave (no barriers)
    for (int off = 32; off >= 1; off >>= 1)
        lmax = fmaxf(lmax, __shfl_xor(lmax, off, 64));
    if ((tid & 63) == 0) atomicMax(&dwmax[blk], __float_as_uint(lmax));

    unsigned short* yp = y + (size_t)(b * CIN + c) * NPAD;
#pragma unroll
    for (int i = 0; i < 4; ++i) {
        int q = tid + i * 256;
        if ((i < 3) || (tid < 16)) {
            ushort4 o;
            o.x = f2bf(vals[i][0]); o.y = f2bf(vals[i][1]);
            o.z = f2bf(vals[i][2]); o.w = f2bf(vals[i][3]);
            *(ushort4*)(yp + q * 4) = o;
        }
    }
    if (tid < 16) *(ushort4*)(yp + HW + tid * 4) = make_ushort4(0, 0, 0, 0);
}

// ---------------- K2: pointwise GEMM (bf16 MFMA) + dw-cut + BN2 + ReLU ----
// Z_b (O x HW) = W' (O x C) * Y_b(C x HW), rows k with dwmax[b,k] < 4 -> 0.
__global__ __launch_bounds__(256) void pw_kernel(
        const unsigned short* __restrict__ y, const unsigned short* __restrict__ Wp,
        const float* __restrict__ b2, const float* __restrict__ dwm,
        float* __restrict__ z, unsigned* __restrict__ pwmax) {
    __shared__ __align__(16) unsigned short Al[128 * 64];  // [m][k], chunk-swizzled by (m&7)
    __shared__ __align__(16) unsigned short Bl[128 * 64];  // [n][k], chunk-swizzled by ((n>>2)&7)

    int bid = blockIdx.x;
    int mt = bid & 1;
    int rest = bid >> 1;
    int nt = rest % 25;
    int b = rest / 25;
    int m0 = mt * 128, n0 = nt * 128;

    int tid = threadIdx.x;
    int lane = tid & 63, wid = tid >> 6;
    int wm = (wid & 1) * 64, wn = (wid >> 1) * 64;
    int l15 = lane & 15, l4 = lane >> 4;

    const unsigned short* yb = y + (size_t)b * CIN * NPAD;
    const float* dwb_ = dwm + b * 256;

    // per-thread staging maps
    int am[4], acch[4];
    const unsigned short* asrc[4];
#pragma unroll
    for (int i = 0; i < 4; ++i) {
        int s = i * 256 + tid;
        int m = s >> 3, cch = s & 7, dch = cch ^ (m & 7);
        am[i] = m; acch[i] = cch;
        asrc[i] = Wp + (size_t)(m0 + m) * CIN + dch * 8;
    }
    int bq[2], bnq[2];
    const unsigned short* bsrc[2];
#pragma unroll
    for (int i = 0; i < 2; ++i) {
        int u = tid + i * 256;
        bq[i] = u >> 5; bnq[i] = u & 31;
        bsrc[i] = yb + (size_t)(bq[i] * 4) * NPAD + n0 + bnq[i] * 4;
    }

    uint4 areg[4];
    uint2 breg[2][4];
    float4 fl[2];
#pragma unroll
    for (int i = 0; i < 4; ++i) areg[i] = *(const uint4*)(asrc[i]);
#pragma unroll
    for (int i = 0; i < 2; ++i) {
#pragma unroll
        for (int r = 0; r < 4; ++r) breg[i][r] = *(const uint2*)(bsrc[i] + r * NPAD);
        fl[i] = *(const float4*)(dwb_ + bq[i] * 4);
    }

    f32x4 acc[4][4];
#pragma unroll
    for (int mf = 0; mf < 4; ++mf)
#pragma unroll
        for (int nf = 0; nf < 4; ++nf) acc[mf][nf] = {0.f, 0.f, 0.f, 0.f};

#pragma unroll
    for (int kk = 0; kk < 4; ++kk) {
        __builtin_amdgcn_s_barrier();      // all waves done reading LDS (iter 0: no-op)
        __builtin_amdgcn_sched_barrier(0);
        // A: store prefetched regs (swizzled slots)
#pragma unroll
        for (int i = 0; i < 4; ++i)
            *(uint4*)((char*)Al + am[i] * 128 + acch[i] * 16) = areg[i];
        // B: apply dw-cut mask, pack transpose from regs, store (swizzled)
#pragma unroll
        for (int i = 0; i < 2; ++i) {
            unsigned mk0 = fl[i].x >= 4.0f ? 0xffffffffu : 0u;
            unsigned mk1 = fl[i].y >= 4.0f ? 0xffffffffu : 0u;
            unsigned mk2 = fl[i].z >= 4.0f ? 0xffffffffu : 0u;
            unsigned mk3 = fl[i].w >= 4.0f ? 0xffffffffu : 0u;
            uint2 r0 = breg[i][0], r1 = breg[i][1], r2 = breg[i][2], r3 = breg[i][3];
            r0.x &= mk0; r0.y &= mk0; r1.x &= mk1; r1.y &= mk1;
            r2.x &= mk2; r2.y &= mk2; r3.x &= mk3; r3.y &= mk3;
            int q = bq[i], nq = bnq[i];
#pragma unroll
            for (int i2 = 0; i2 < 4; ++i2) {
                unsigned x0 = (i2 & 2) ? r0.y : r0.x;
                unsigned x1 = (i2 & 2) ? r1.y : r1.x;
                unsigned x2 = (i2 & 2) ? r2.y : r2.x;
                unsigned x3 = (i2 & 2) ? r3.y : r3.x;
                if (i2 & 1) { x0 >>= 16; x2 >>= 16; }
                else        { x0 &= 0xffffu; x2 &= 0xffffu; }
                unsigned px = (i2 & 1) ? (x0 | (x1 & 0xffff0000u))
                                       : (x0 | (x1 << 16));
                unsigned py = (i2 & 1) ? (x2 | (x3 & 0xffff0000u))
                                       : (x2 | (x3 << 16));
                int nloc = nq * 4 + i2;
                int sb = nloc * 128 + (((q >> 1) ^ ((nloc >> 2) & 7)) << 4) + ((q & 1) << 3);
                *(uint2*)((char*)Bl + sb) = make_uint2(px, py);
            }
        }
        // prefetch next K-step into regs (stays in flight across the barrier)
        if (kk < 3) {
#pragma unroll
            for (int i = 0; i < 4; ++i)
                areg[i] = *(const uint4*)(asrc[i] + (kk + 1) * 64);
#pragma unroll
            for (int i = 0; i < 2; ++i) {
#pragma unroll
                for (int r = 0; r < 4; ++r)
                    breg[i][r] = *(const uint2*)(bsrc[i] + (size_t)(kk + 1) * 64 * NPAD + r * NPAD);
                fl[i] = *(const float4*)(dwb_ + (kk + 1) * 64 + bq[i] * 4);
            }
        }
        asm volatile("s_waitcnt lgkmcnt(0)" ::: "memory");  // LDS writes visible; vmcnt NOT drained
        __builtin_amdgcn_s_barrier();
        __builtin_amdgcn_sched_barrier(0);
        // compute this K-step: 2 halves of K=32
#pragma unroll
        for (int h = 0; h < 2; ++h) {
            bf16x8 af[4], bfr[4];
            int cc = h * 4 + l4;
#pragma unroll
            for (int mf = 0; mf < 4; ++mf) {
                int m = wm + mf * 16 + l15;
                af[mf] = *(const bf16x8*)((const char*)Al + m * 128 + ((cc ^ (m & 7)) << 4));
            }
#pragma unroll
            for (int nf = 0; nf < 4; ++nf) {
                int n = wn + nf * 16 + l15;
                bfr[nf] = *(const bf16x8*)((const char*)Bl + n * 128 + ((cc ^ ((n >> 2) & 7)) << 4));
            }
#pragma unroll
            for (int mf = 0; mf < 4; ++mf)
#pragma unroll
                for (int nf = 0; nf < 4; ++nf)
                    acc[mf][nf] = __builtin_amdgcn_mfma_f32_16x16x32_bf16(
                        af[mf], bfr[nf], acc[mf][nf], 0, 0, 0);
        }
    }

    // epilogue: bias + relu + store + per-o-row plane max (atomic)
    float* zb = z + (size_t)b * COUT * HW;
#pragma unroll
    for (int mf = 0; mf < 4; ++mf) {
        int obase = m0 + wm + mf * 16 + l4 * 4;
        float bb0 = b2[obase + 0], bb1 = b2[obase + 1];
        float bb2v = b2[obase + 2], bb3 = b2[obase + 3];
        float rmax[4] = {0.f, 0.f, 0.f, 0.f};
#pragma unroll
        for (int nf = 0; nf < 4; ++nf) {
            int n = n0 + wn + nf * 16 + l15;
            bool valid = (n < HW);
            float v0 = fmaxf(acc[mf][nf][0] + bb0, 0.f);
            float v1 = fmaxf(acc[mf][nf][1] + bb1, 0.f);
            float v2 = fmaxf(acc[mf][nf][2] + bb2v, 0.f);
            float v3 = fmaxf(acc[mf][nf][3] + bb3, 0.f);
            if (valid) {
                zb[(size_t)(obase + 0) * HW + n] = v0;
                zb[(size_t)(obase + 1) * HW + n] = v1;
                zb[(size_t)(obase + 2) * HW + n] = v2;
                zb[(size_t)(obase + 3) * HW + n] = v3;
                rmax[0] = fmaxf(rmax[0], v0);
                rmax[1] = fmaxf(rmax[1], v1);
                rmax[2] = fmaxf(rmax[2], v2);
                rmax[3] = fmaxf(rmax[3], v3);
            }
        }
#pragma unroll
        for (int r = 0; r < 4; ++r) {
            float v = rmax[r];
            v = fmaxf(v, __shfl_xor(v, 1, 64));
            v = fmaxf(v, __shfl_xor(v, 2, 64));
            v = fmaxf(v, __shfl_xor(v, 4, 64));
            v = fmaxf(v, __shfl_xor(v, 8, 64));
            if (l15 == 0)
                atomicMax(&pwmax[b * COUT + obase + r], __float_as_uint(v));
        }
    }
}

// ---------------- K3: apply pointwise cut ---------------------------------
__global__ __launch_bounds__(256) void cut_kernel(const unsigned* __restrict__ pwmax,
                                                  float* __restrict__ z) {
    int base = blockIdx.x * 8;
#pragma unroll
    for (int j = 0; j < 8; ++j) {
        int bo = base + j;
        if (__uint_as_float(pwmax[bo]) >= 1e-3f) continue;
        float4* zp = (float4*)(z + (size_t)bo * HW);
        for (int i = threadIdx.x; i < HW / 4; i += 256)
            zp[i] = make_float4(0.f, 0.f, 0.f, 0.f);
    }
}

extern "C" void kernel_launch(void* const* d_in, const int* in_sizes, int n_in,
                              void* d_out, int out_size, void* d_ws, size_t ws_size,
                              hipStream_t stream) {
    const float* x   = (const float*)d_in[0];
    const float* dww = (const float*)d_in[1];
    const float* dwb = (const float*)d_in[2];
    const float* g1  = (const float*)d_in[3];
    const float* be1 = (const float*)d_in[4];
    const float* mu1 = (const float*)d_in[5];
    const float* va1 = (const float*)d_in[6];
    const float* pww = (const float*)d_in[7];
    const float* pwb = (const float*)d_in[8];
    const float* g2  = (const float*)d_in[9];
    const float* be2 = (const float*)d_in[10];
    const float* mu2 = (const float*)d_in[11];
    const float* va2 = (const float*)d_in[12];
    float* z = (float*)d_out;

    char* ws = (char*)d_ws;
    const size_t Y_BYTES = (size_t)BATCH * CIN * NPAD * 2;  // 52,428,800
    unsigned short* y  = (unsigned short*)ws;
    unsigned short* Wp = (unsigned short*)(ws + Y_BYTES);
    float* b2          = (float*)(ws + Y_BYTES + 131072);
    unsigned* pwmax    = (unsigned*)(ws + Y_BYTES + 131072 + 1024);
    unsigned* dwmax    = (unsigned*)(ws + Y_BYTES + 131072 + 1024 + 32768);

    prep_kernel<<<256, 256, 0, stream>>>(pww, pwb, g2, be2, mu2, va2, Wp, b2, pwmax, dwmax);
    dw_kernel<<<BATCH * CIN, 256, 0, stream>>>(x, dww, dwb, g1, be1, mu1, va1, y, dwmax);
    pw_kernel<<<2 * 25 * BATCH, 256, 0, stream>>>(y, Wp, b2, (const float*)dwmax, z, pwmax);
    cut_kernel<<<BATCH * COUT / 8, 256, 0, stream>>>(pwmax, z);
}

// Round 4
// 112.645 us; speedup vs baseline: 1.0739x; 1.0688x over previous
//
#include <hip/hip_runtime.h>
#include <hip/hip_bf16.h>
#include <stdint.h>

#define BATCH 32
#define CIN   256
#define COUT  256
#define HW    3136   // 56*56
#define NPAD  3200   // pad HW to multiple of 128

typedef short bf16x8 __attribute__((ext_vector_type(8)));
typedef float f32x4  __attribute__((ext_vector_type(4)));

__device__ __forceinline__ unsigned short f2bf(float f) {
    unsigned u = __float_as_uint(f);
    u += 0x7fffu + ((u >> 16) & 1u);   // round-to-nearest-even
    return (unsigned short)(u >> 16);
}

// ---------------- K0: fold BN2 into pw weights; zero pwmax -----------------
__global__ __launch_bounds__(256) void prep_kernel(
        const float* __restrict__ pw_w, const float* __restrict__ pw_b,
        const float* __restrict__ g2, const float* __restrict__ be2,
        const float* __restrict__ mu2, const float* __restrict__ va2,
        unsigned short* __restrict__ Wp, float* __restrict__ b2,
        unsigned* __restrict__ pwmax) {
    int o = blockIdx.x;
    int t = threadIdx.x;
    float inv2 = g2[o] * rsqrtf(va2[o] + 1e-5f);
    Wp[o * CIN + t] = f2bf(pw_w[o * CIN + t] * inv2);
    if (t == 0) b2[o] = pw_b[o] * inv2 + be2[o] - mu2[o] * inv2;
    int idx = blockIdx.x * 256 + t;
    if (idx < BATCH * COUT) pwmax[idx] = 0u;
}

// ---------------- K1: depthwise 3x3 + BN1 + ReLU -> y bf16 (UNCUT) --------
// Row-rolling: thread owns an 8-col x 14-row strip; 3 input rows live in
// registers; per output row: 4 loads, 72 fma, one 16B store. 8 planes/block.
#define LOADROW(dst, rp, mrow) do {                                        \
    float4 v0_ = *(const float4*)((rp) + c0);                              \
    float4 v1_ = *(const float4*)((rp) + c0 + 4);                          \
    dst[0] = (rp)[lidx] * (msL * (mrow));                                  \
    dst[1] = v0_.x * (mrow); dst[2] = v0_.y * (mrow);                      \
    dst[3] = v0_.z * (mrow); dst[4] = v0_.w * (mrow);                      \
    dst[5] = v1_.x * (mrow); dst[6] = v1_.y * (mrow);                      \
    dst[7] = v1_.z * (mrow); dst[8] = v1_.w * (mrow);                      \
    dst[9] = (rp)[ridx] * (msR * (mrow));                                  \
} while (0)

__global__ __launch_bounds__(256, 3) void dw_kernel(
        const float* __restrict__ x, const float* __restrict__ dww,
        const float* __restrict__ dwb,
        const float* __restrict__ g1, const float* __restrict__ be1,
        const float* __restrict__ mu1, const float* __restrict__ va1,
        unsigned short* __restrict__ y, float* __restrict__ dwmax) {
    int tid = threadIdx.x;
    int blk = blockIdx.x;              // 1024 blocks x 8 planes
    __shared__ float lmx[256];

    float lmax = 0.f;
    if (tid < 224) {
        int p    = tid / 28;           // plane in block 0..7
        int r28  = tid - p * 28;
        int band = r28 / 7;            // 0..3 -> rows band*14..+13
        int sc   = r28 - band * 7;     // 0..6 -> cols sc*8..+7
        int plane = blk * 8 + p;       // global b*256+c
        int c = plane & 255;
        int r0 = band * 14;
        int c0 = sc * 8;

        const float* xq = x + (size_t)plane * HW;
        float w00 = dww[c*9+0], w01 = dww[c*9+1], w02 = dww[c*9+2];
        float w10 = dww[c*9+3], w11 = dww[c*9+4], w12 = dww[c*9+5];
        float w20 = dww[c*9+6], w21 = dww[c*9+7], w22 = dww[c*9+8];
        float inv = g1[c] * rsqrtf(va1[c] + 1e-5f);
        float b0  = dwb[c] * inv + (be1[c] - mu1[c] * inv);

        float msL  = (sc == 0) ? 0.f : 1.f;
        float msR  = (sc == 6) ? 0.f : 1.f;
        int   lidx = (sc == 0) ? c0 : c0 - 1;
        int   ridx = (sc == 6) ? c0 + 7 : c0 + 8;
        float mTop = (band == 0) ? 0.f : 1.f;
        float mBot = (band == 3) ? 0.f : 1.f;

        float A[10], Bv[10], Cv[10], nx[10];
        {   // A = row r0-1 (clamped, zeroed for band 0)
            const float* rp = xq + ((band == 0) ? 0 : (r0 - 1)) * 56;
            LOADROW(A, rp, mTop);
        }
        {   // B = row r0 (always valid)
            const float* rp = xq + r0 * 56;
            LOADROW(Bv, rp, 1.f);
        }
        {   // prefetch C = row r0+1 (always valid: max 43)
            const float* rp = xq + (r0 + 1) * 56;
            LOADROW(nx, rp, 1.f);
        }
        unsigned short* yq = y + (size_t)plane * NPAD + c0;

#pragma unroll
        for (int i = 0; i < 14; ++i) {
#pragma unroll
            for (int t2 = 0; t2 < 10; ++t2) Cv[t2] = nx[t2];
            if (i < 13) {   // prefetch row r0+i+2; only band3@i==12 invalid
                const float* rp = xq + ((i == 12) ? ((band == 3) ? 55 : (r0 + 14))
                                                  : (r0 + i + 2)) * 56;
                if (i == 12) { LOADROW(nx, rp, mBot); }
                else         { LOADROW(nx, rp, 1.f); }
            }
            unsigned us[8];
#pragma unroll
            for (int j = 0; j < 8; ++j) {
                float o = fmaf(A[j],    w00, fmaf(A[j+1],  w01, fmaf(A[j+2],  w02,
                          fmaf(Bv[j],   w10, fmaf(Bv[j+1], w11, fmaf(Bv[j+2], w12,
                          fmaf(Cv[j],   w20, fmaf(Cv[j+1], w21, Cv[j+2] * w22))))))));
                float v = fmaxf(fmaf(o, inv, b0), 0.f);
                lmax = fmaxf(lmax, v);
                us[j] = f2bf(v);
            }
            uint4 st;
            st.x = us[0] | (us[1] << 16);
            st.y = us[2] | (us[3] << 16);
            st.z = us[4] | (us[5] << 16);
            st.w = us[6] | (us[7] << 16);
            *(uint4*)(yq + (r0 + i) * 56) = st;
#pragma unroll
            for (int t2 = 0; t2 < 10; ++t2) { A[t2] = Bv[t2]; Bv[t2] = Cv[t2]; }
        }
    }
    lmx[tid] = lmax;
    __syncthreads();
    if (tid < 8) {     // block exclusively owns its 8 planes: plain store
        float m = 0.f;
#pragma unroll 4
        for (int j = 0; j < 28; ++j) m = fmaxf(m, lmx[tid * 28 + j]);
        dwmax[blk * 8 + tid] = m;
    }
    if (tid < 64) {    // zero pad columns (HW..NPAD) of each plane
        int p = tid >> 3;
        uint4* dst = (uint4*)(y + (size_t)(blk * 8 + p) * NPAD + HW) + (tid & 7);
        *dst = make_uint4(0, 0, 0, 0);
    }
}

// ---------------- K2: pointwise GEMM (bf16 MFMA) + dw-cut + BN2 + ReLU ----
// Z_b (O x HW) = W' (O x C) * Y_b(C x HW), rows k with dwmax[b,k] < 4 -> 0.
__global__ __launch_bounds__(256) void pw_kernel(
        const unsigned short* __restrict__ y, const unsigned short* __restrict__ Wp,
        const float* __restrict__ b2, const float* __restrict__ dwm,
        float* __restrict__ z, unsigned* __restrict__ pwmax) {
    __shared__ __align__(16) unsigned short Al[128 * 64];  // [m][k], chunk-swizzled by (m&7)
    __shared__ __align__(16) unsigned short Bl[128 * 64];  // [n][k], chunk-swizzled by ((n>>2)&7)

    int bid0 = blockIdx.x;                      // 1600
    int bid = (bid0 & 7) * 200 + (bid0 >> 3);   // XCD-pairing swizzle (bijective)
    int mt = bid & 1;
    int rest = bid >> 1;
    int nt = rest % 25;
    int b = rest / 25;
    int m0 = mt * 128, n0 = nt * 128;

    int tid = threadIdx.x;
    int lane = tid & 63, wid = tid >> 6;
    int wm = (wid & 1) * 64, wn = (wid >> 1) * 64;
    int l15 = lane & 15, l4 = lane >> 4;

    const unsigned short* yb = y + (size_t)b * CIN * NPAD;
    const float* dwb_ = dwm + b * 256;

    // per-thread staging maps
    int am[4], acch[4];
    const unsigned short* asrc[4];
#pragma unroll
    for (int i = 0; i < 4; ++i) {
        int s = i * 256 + tid;
        int m = s >> 3, cch = s & 7, dch = cch ^ (m & 7);
        am[i] = m; acch[i] = cch;
        asrc[i] = Wp + (size_t)(m0 + m) * CIN + dch * 8;
    }
    int bq[2], bnq[2];
    const unsigned short* bsrc[2];
#pragma unroll
    for (int i = 0; i < 2; ++i) {
        int u = tid + i * 256;
        bq[i] = u >> 5; bnq[i] = u & 31;
        bsrc[i] = yb + (size_t)(bq[i] * 4) * NPAD + n0 + bnq[i] * 4;
    }

    uint4 areg[4];
    uint2 breg[2][4];
    float4 fl[2];
#pragma unroll
    for (int i = 0; i < 4; ++i) areg[i] = *(const uint4*)(asrc[i]);
#pragma unroll
    for (int i = 0; i < 2; ++i) {
#pragma unroll
        for (int r = 0; r < 4; ++r) breg[i][r] = *(const uint2*)(bsrc[i] + r * NPAD);
        fl[i] = *(const float4*)(dwb_ + bq[i] * 4);
    }

    f32x4 acc[4][4];
#pragma unroll
    for (int mf = 0; mf < 4; ++mf)
#pragma unroll
        for (int nf = 0; nf < 4; ++nf) acc[mf][nf] = {0.f, 0.f, 0.f, 0.f};

#pragma unroll
    for (int kk = 0; kk < 4; ++kk) {
        __builtin_amdgcn_s_barrier();      // all waves done reading LDS (iter 0: no-op)
        __builtin_amdgcn_sched_barrier(0);
        // A: store prefetched regs (swizzled slots)
#pragma unroll
        for (int i = 0; i < 4; ++i)
            *(uint4*)((char*)Al + am[i] * 128 + acch[i] * 16) = areg[i];
        // B: apply dw-cut mask, pack transpose from regs, store (swizzled)
#pragma unroll
        for (int i = 0; i < 2; ++i) {
            unsigned mk0 = fl[i].x >= 4.0f ? 0xffffffffu : 0u;
            unsigned mk1 = fl[i].y >= 4.0f ? 0xffffffffu : 0u;
            unsigned mk2 = fl[i].z >= 4.0f ? 0xffffffffu : 0u;
            unsigned mk3 = fl[i].w >= 4.0f ? 0xffffffffu : 0u;
            uint2 r0 = breg[i][0], r1 = breg[i][1], r2 = breg[i][2], r3 = breg[i][3];
            r0.x &= mk0; r0.y &= mk0; r1.x &= mk1; r1.y &= mk1;
            r2.x &= mk2; r2.y &= mk2; r3.x &= mk3; r3.y &= mk3;
            int q = bq[i], nq = bnq[i];
#pragma unroll
            for (int i2 = 0; i2 < 4; ++i2) {
                unsigned x0 = (i2 & 2) ? r0.y : r0.x;
                unsigned x1 = (i2 & 2) ? r1.y : r1.x;
                unsigned x2 = (i2 & 2) ? r2.y : r2.x;
                unsigned x3 = (i2 & 2) ? r3.y : r3.x;
                if (i2 & 1) { x0 >>= 16; x2 >>= 16; }
                else        { x0 &= 0xffffu; x2 &= 0xffffu; }
                unsigned px = (i2 & 1) ? (x0 | (x1 & 0xffff0000u))
                                       : (x0 | (x1 << 16));
                unsigned py = (i2 & 1) ? (x2 | (x3 & 0xffff0000u))
                                       : (x2 | (x3 << 16));
                int nloc = nq * 4 + i2;
                int sb = nloc * 128 + (((q >> 1) ^ ((nloc >> 2) & 7)) << 4) + ((q & 1) << 3);
                *(uint2*)((char*)Bl + sb) = make_uint2(px, py);
            }
        }
        // prefetch next K-step into regs (stays in flight across the barrier)
        if (kk < 3) {
#pragma unroll
            for (int i = 0; i < 4; ++i)
                areg[i] = *(const uint4*)(asrc[i] + (kk + 1) * 64);
#pragma unroll
            for (int i = 0; i < 2; ++i) {
#pragma unroll
                for (int r = 0; r < 4; ++r)
                    breg[i][r] = *(const uint2*)(bsrc[i] + (size_t)(kk + 1) * 64 * NPAD + r * NPAD);
                fl[i] = *(const float4*)(dwb_ + (kk + 1) * 64 + bq[i] * 4);
            }
        }
        asm volatile("s_waitcnt lgkmcnt(0)" ::: "memory");  // LDS writes visible; vmcnt NOT drained
        __builtin_amdgcn_s_barrier();
        __builtin_amdgcn_sched_barrier(0);
        // compute this K-step: 2 halves of K=32
#pragma unroll
        for (int h = 0; h < 2; ++h) {
            bf16x8 af[4], bfr[4];
            int cc = h * 4 + l4;
#pragma unroll
            for (int mf = 0; mf < 4; ++mf) {
                int m = wm + mf * 16 + l15;
                af[mf] = *(const bf16x8*)((const char*)Al + m * 128 + ((cc ^ (m & 7)) << 4));
            }
#pragma unroll
            for (int nf = 0; nf < 4; ++nf) {
                int n = wn + nf * 16 + l15;
                bfr[nf] = *(const bf16x8*)((const char*)Bl + n * 128 + ((cc ^ ((n >> 2) & 7)) << 4));
            }
#pragma unroll
            for (int mf = 0; mf < 4; ++mf)
#pragma unroll
                for (int nf = 0; nf < 4; ++nf)
                    acc[mf][nf] = __builtin_amdgcn_mfma_f32_16x16x32_bf16(
                        af[mf], bfr[nf], acc[mf][nf], 0, 0, 0);
        }
    }

    // epilogue: bias + relu + store + per-o-row plane max (atomic)
    float* zb = z + (size_t)b * COUT * HW;
#pragma unroll
    for (int mf = 0; mf < 4; ++mf) {
        int obase = m0 + wm + mf * 16 + l4 * 4;
        float bb0 = b2[obase + 0], bb1 = b2[obase + 1];
        float bb2v = b2[obase + 2], bb3 = b2[obase + 3];
        float rmax[4] = {0.f, 0.f, 0.f, 0.f};
#pragma unroll
        for (int nf = 0; nf < 4; ++nf) {
            int n = n0 + wn + nf * 16 + l15;
            bool valid = (n < HW);
            float v0 = fmaxf(acc[mf][nf][0] + bb0, 0.f);
            float v1 = fmaxf(acc[mf][nf][1] + bb1, 0.f);
            float v2 = fmaxf(acc[mf][nf][2] + bb2v, 0.f);
            float v3 = fmaxf(acc[mf][nf][3] + bb3, 0.f);
            if (valid) {
                zb[(size_t)(obase + 0) * HW + n] = v0;
                zb[(size_t)(obase + 1) * HW + n] = v1;
                zb[(size_t)(obase + 2) * HW + n] = v2;
                zb[(size_t)(obase + 3) * HW + n] = v3;
                rmax[0] = fmaxf(rmax[0], v0);
                rmax[1] = fmaxf(rmax[1], v1);
                rmax[2] = fmaxf(rmax[2], v2);
                rmax[3] = fmaxf(rmax[3], v3);
            }
        }
#pragma unroll
        for (int r = 0; r < 4; ++r) {
            float v = rmax[r];
            v = fmaxf(v, __shfl_xor(v, 1, 64));
            v = fmaxf(v, __shfl_xor(v, 2, 64));
            v = fmaxf(v, __shfl_xor(v, 4, 64));
            v = fmaxf(v, __shfl_xor(v, 8, 64));
            if (l15 == 0)
                atomicMax(&pwmax[b * COUT + obase + r], __float_as_uint(v));
        }
    }
}

// ---------------- K3: apply pointwise cut ---------------------------------
__global__ __launch_bounds__(256) void cut_kernel(const unsigned* __restrict__ pwmax,
                                                  float* __restrict__ z) {
    int base = blockIdx.x * 8;
#pragma unroll
    for (int j = 0; j < 8; ++j) {
        int bo = base + j;
        if (__uint_as_float(pwmax[bo]) >= 1e-3f) continue;
        float4* zp = (float4*)(z + (size_t)bo * HW);
        for (int i = threadIdx.x; i < HW / 4; i += 256)
            zp[i] = make_float4(0.f, 0.f, 0.f, 0.f);
    }
}

extern "C" void kernel_launch(void* const* d_in, const int* in_sizes, int n_in,
                              void* d_out, int out_size, void* d_ws, size_t ws_size,
                              hipStream_t stream) {
    const float* x   = (const float*)d_in[0];
    const float* dww = (const float*)d_in[1];
    const float* dwb = (const float*)d_in[2];
    const float* g1  = (const float*)d_in[3];
    const float* be1 = (const float*)d_in[4];
    const float* mu1 = (const float*)d_in[5];
    const float* va1 = (const float*)d_in[6];
    const float* pww = (const float*)d_in[7];
    const float* pwb = (const float*)d_in[8];
    const float* g2  = (const float*)d_in[9];
    const float* be2 = (const float*)d_in[10];
    const float* mu2 = (const float*)d_in[11];
    const float* va2 = (const float*)d_in[12];
    float* z = (float*)d_out;

    char* ws = (char*)d_ws;
    const size_t Y_BYTES = (size_t)BATCH * CIN * NPAD * 2;  // 52,428,800
    unsigned short* y  = (unsigned short*)ws;
    unsigned short* Wp = (unsigned short*)(ws + Y_BYTES);
    float* b2          = (float*)(ws + Y_BYTES + 131072);
    unsigned* pwmax    = (unsigned*)(ws + Y_BYTES + 131072 + 1024);
    float* dwmax       = (float*)(ws + Y_BYTES + 131072 + 1024 + 32768);

    prep_kernel<<<256, 256, 0, stream>>>(pww, pwb, g2, be2, mu2, va2, Wp, b2, pwmax);
    dw_kernel<<<1024, 256, 0, stream>>>(x, dww, dwb, g1, be1, mu1, va1, y, dwmax);
    pw_kernel<<<1600, 256, 0, stream>>>(y, Wp, b2, dwmax, z, pwmax);
    cut_kernel<<<BATCH * COUT / 8, 256, 0, stream>>>(pwmax, z);
}

// Round 5
// 99.409 us; speedup vs baseline: 1.2168x; 1.1331x over previous
//
#include <hip/hip_runtime.h>
#include <hip/hip_bf16.h>
#include <stdint.h>

#define BATCH 32
#define CIN   256
#define COUT  256
#define HW    3136   // 56*56
#define NPAD  3200   // pad HW to multiple of 128

typedef short bf16x8 __attribute__((ext_vector_type(8)));
typedef float f32x4  __attribute__((ext_vector_type(4)));

__device__ __forceinline__ unsigned short f2bf(float f) {
    unsigned u = __float_as_uint(f);
    u += 0x7fffu + ((u >> 16) & 1u);   // round-to-nearest-even
    return (unsigned short)(u >> 16);
}

// ---------------- K0: fold BN2 into pw weights; zero pwmax -----------------
__global__ __launch_bounds__(256) void prep_kernel(
        const float* __restrict__ pw_w, const float* __restrict__ pw_b,
        const float* __restrict__ g2, const float* __restrict__ be2,
        const float* __restrict__ mu2, const float* __restrict__ va2,
        unsigned short* __restrict__ Wp, float* __restrict__ b2,
        unsigned* __restrict__ pwmax) {
    int o = blockIdx.x;
    int t = threadIdx.x;
    float inv2 = g2[o] * rsqrtf(va2[o] + 1e-5f);
    Wp[o * CIN + t] = f2bf(pw_w[o * CIN + t] * inv2);
    if (t == 0) b2[o] = pw_b[o] * inv2 + be2[o] - mu2[o] * inv2;
    int idx = blockIdx.x * 256 + t;
    if (idx < BATCH * COUT) pwmax[idx] = 0u;
}

// ---------------- K1: depthwise 3x3 + BN1 + ReLU -> y bf16 (UNCUT) --------
// Thread = 8-col x 14-row strip. 5-row register window (A,B,C,N1,N2):
// 3-deep row prefetch. Edge handling: 2 masked scalars per row; top/bottom
// rows masked once. Pack via v_cvt_pk_bf16_f32.
__global__ __launch_bounds__(256) void dw_kernel(
        const float* __restrict__ x, const float* __restrict__ dww,
        const float* __restrict__ dwb,
        const float* __restrict__ g1, const float* __restrict__ be1,
        const float* __restrict__ mu1, const float* __restrict__ va1,
        unsigned short* __restrict__ y, float* __restrict__ dwmax) {
    int tid = threadIdx.x;
    int blk = blockIdx.x;              // 1024 blocks x 8 planes
    __shared__ float lmx[256];

    float lmax = 0.f;
    if (tid < 224) {
        int p    = tid / 28;           // plane in block 0..7
        int r28  = tid - p * 28;
        int band = r28 / 7;            // 0..3 -> rows band*14..+13
        int sc   = r28 - band * 7;     // 0..6 -> cols sc*8..+7
        int plane = blk * 8 + p;       // global b*256+c
        int c = plane & 255;
        int r0 = band * 14;
        int c0 = sc * 8;

        const float* xq = x + (size_t)plane * HW;
        float w00 = dww[c*9+0], w01 = dww[c*9+1], w02 = dww[c*9+2];
        float w10 = dww[c*9+3], w11 = dww[c*9+4], w12 = dww[c*9+5];
        float w20 = dww[c*9+6], w21 = dww[c*9+7], w22 = dww[c*9+8];
        float inv = g1[c] * rsqrtf(va1[c] + 1e-5f);
        float b0  = dwb[c] * inv + (be1[c] - mu1[c] * inv);

        float msL  = (sc == 0) ? 0.f : 1.f;
        float msR  = (sc == 6) ? 0.f : 1.f;
        int   lidx = (sc == 0) ? c0 : c0 - 1;
        int   ridx = (sc == 6) ? c0 + 7 : c0 + 8;
        float mTop = (band == 0) ? 0.f : 1.f;
        float mBot = (band == 3) ? 0.f : 1.f;

        float A[10], Bv[10], Cv[10], N1[10], N2[10];

        // plain row load: only the 2 edge scalars are masked
#define LR(dst, q) do {                                                    \
        const float* rp_ = xq + (q) * 56;                                  \
        float4 u0_ = *(const float4*)(rp_ + c0);                           \
        float4 u1_ = *(const float4*)(rp_ + c0 + 4);                       \
        dst[0] = rp_[lidx] * msL;                                          \
        dst[1] = u0_.x; dst[2] = u0_.y; dst[3] = u0_.z; dst[4] = u0_.w;    \
        dst[5] = u1_.x; dst[6] = u1_.y; dst[7] = u1_.z; dst[8] = u1_.w;    \
        dst[9] = rp_[ridx] * msR;                                          \
} while (0)

        // init window: A=row r0-1 (masked for band0), B..N2 = rows r0..r0+3
        LR(A, (band == 0) ? 0 : (r0 - 1));
#pragma unroll
        for (int t2 = 0; t2 < 10; ++t2) A[t2] *= mTop;
        LR(Bv, r0);
        LR(Cv, r0 + 1);
        LR(N1, r0 + 2);
        LR(N2, r0 + 3);

        unsigned short* yq = y + (size_t)plane * NPAD + c0;

#pragma unroll
        for (int i = 0; i < 14; ++i) {
            float v[8];
#pragma unroll
            for (int j = 0; j < 8; ++j) {
                float o = fmaf(A[j],    w00, fmaf(A[j+1],  w01, fmaf(A[j+2],  w02,
                          fmaf(Bv[j],   w10, fmaf(Bv[j+1], w11, fmaf(Bv[j+2], w12,
                          fmaf(Cv[j],   w20, fmaf(Cv[j+1], w21, Cv[j+2] * w22))))))));
                v[j] = fmaxf(fmaf(o, inv, b0), 0.f);
            }
            lmax = fmaxf(lmax, fmaxf(v[0], v[1]));
            lmax = fmaxf(lmax, fmaxf(v[2], v[3]));
            lmax = fmaxf(lmax, fmaxf(v[4], v[5]));
            lmax = fmaxf(lmax, fmaxf(v[6], v[7]));
            uint4 st;
            asm("v_cvt_pk_bf16_f32 %0, %1, %2" : "=v"(st.x) : "v"(v[0]), "v"(v[1]));
            asm("v_cvt_pk_bf16_f32 %0, %1, %2" : "=v"(st.y) : "v"(v[2]), "v"(v[3]));
            asm("v_cvt_pk_bf16_f32 %0, %1, %2" : "=v"(st.z) : "v"(v[4]), "v"(v[5]));
            asm("v_cvt_pk_bf16_f32 %0, %1, %2" : "=v"(st.w) : "v"(v[6]), "v"(v[7]));
            *(uint4*)(yq + (r0 + i) * 56) = st;
            // shift window
#pragma unroll
            for (int t2 = 0; t2 < 10; ++t2) {
                A[t2] = Bv[t2]; Bv[t2] = Cv[t2]; Cv[t2] = N1[t2]; N1[t2] = N2[t2];
            }
            // refill N2 = row r0+i+4 (last needed: r0+14 at i==10)
            if (i < 10) {
                LR(N2, r0 + i + 4);
            } else if (i == 10) {
                LR(N2, (band == 3) ? 55 : (r0 + 14));
#pragma unroll
                for (int t2 = 0; t2 < 10; ++t2) N2[t2] *= mBot;
            }
        }
#undef LR
    }
    lmx[tid] = lmax;
    __syncthreads();
    if (tid < 8) {     // block exclusively owns its 8 planes: plain store
        float m = 0.f;
#pragma unroll 4
        for (int j = 0; j < 28; ++j) m = fmaxf(m, lmx[tid * 28 + j]);
        dwmax[blk * 8 + tid] = m;
    }
    if (tid < 64) {    // zero pad columns (HW..NPAD) of each plane
        int p = tid >> 3;
        uint4* dst = (uint4*)(y + (size_t)(blk * 8 + p) * NPAD + HW) + (tid & 7);
        *dst = make_uint4(0, 0, 0, 0);
    }
}

// ---------------- K2: pointwise GEMM (bf16 MFMA) + dw-cut + BN2 + ReLU ----
// Z_b (O x HW) = W' (O x C) * Y_b(C x HW), rows k with dwmax[b,k] < 4 -> 0.
__global__ __launch_bounds__(256) void pw_kernel(
        const unsigned short* __restrict__ y, const unsigned short* __restrict__ Wp,
        const float* __restrict__ b2, const float* __restrict__ dwm,
        float* __restrict__ z, unsigned* __restrict__ pwmax) {
    __shared__ __align__(16) unsigned short Al[128 * 64];  // [m][k], chunk-swizzled by (m&7)
    __shared__ __align__(16) unsigned short Bl[128 * 64];  // [n][k], chunk-swizzled by ((n>>2)&7)

    int bid0 = blockIdx.x;                      // 1600
    int bid = (bid0 & 7) * 200 + (bid0 >> 3);   // XCD-pairing swizzle (bijective)
    int mt = bid & 1;
    int rest = bid >> 1;
    int nt = rest % 25;
    int b = rest / 25;
    int m0 = mt * 128, n0 = nt * 128;

    int tid = threadIdx.x;
    int lane = tid & 63, wid = tid >> 6;
    int wm = (wid & 1) * 64, wn = (wid >> 1) * 64;
    int l15 = lane & 15, l4 = lane >> 4;

    const unsigned short* yb = y + (size_t)b * CIN * NPAD;
    const float* dwb_ = dwm + b * 256;

    // per-thread staging maps
    int am[4], acch[4];
    const unsigned short* asrc[4];
#pragma unroll
    for (int i = 0; i < 4; ++i) {
        int s = i * 256 + tid;
        int m = s >> 3, cch = s & 7, dch = cch ^ (m & 7);
        am[i] = m; acch[i] = cch;
        asrc[i] = Wp + (size_t)(m0 + m) * CIN + dch * 8;
    }
    int bq[2], bnq[2];
    const unsigned short* bsrc[2];
#pragma unroll
    for (int i = 0; i < 2; ++i) {
        int u = tid + i * 256;
        bq[i] = u >> 5; bnq[i] = u & 31;
        bsrc[i] = yb + (size_t)(bq[i] * 4) * NPAD + n0 + bnq[i] * 4;
    }

    uint4 areg[4];
    uint2 breg[2][4];
    float4 fl[2];
#pragma unroll
    for (int i = 0; i < 4; ++i) areg[i] = *(const uint4*)(asrc[i]);
#pragma unroll
    for (int i = 0; i < 2; ++i) {
#pragma unroll
        for (int r = 0; r < 4; ++r) breg[i][r] = *(const uint2*)(bsrc[i] + r * NPAD);
        fl[i] = *(const float4*)(dwb_ + bq[i] * 4);
    }

    f32x4 acc[4][4];
#pragma unroll
    for (int mf = 0; mf < 4; ++mf)
#pragma unroll
        for (int nf = 0; nf < 4; ++nf) acc[mf][nf] = {0.f, 0.f, 0.f, 0.f};

#pragma unroll
    for (int kk = 0; kk < 4; ++kk) {
        __builtin_amdgcn_s_barrier();      // all waves done reading LDS (iter 0: no-op)
        __builtin_amdgcn_sched_barrier(0);
        // A: store prefetched regs (swizzled slots)
#pragma unroll
        for (int i = 0; i < 4; ++i)
            *(uint4*)((char*)Al + am[i] * 128 + acch[i] * 16) = areg[i];
        // B: apply dw-cut mask, pack transpose from regs, store (swizzled)
#pragma unroll
        for (int i = 0; i < 2; ++i) {
            unsigned mk0 = fl[i].x >= 4.0f ? 0xffffffffu : 0u;
            unsigned mk1 = fl[i].y >= 4.0f ? 0xffffffffu : 0u;
            unsigned mk2 = fl[i].z >= 4.0f ? 0xffffffffu : 0u;
            unsigned mk3 = fl[i].w >= 4.0f ? 0xffffffffu : 0u;
            uint2 r0 = breg[i][0], r1 = breg[i][1], r2 = breg[i][2], r3 = breg[i][3];
            r0.x &= mk0; r0.y &= mk0; r1.x &= mk1; r1.y &= mk1;
            r2.x &= mk2; r2.y &= mk2; r3.x &= mk3; r3.y &= mk3;
            int q = bq[i], nq = bnq[i];
#pragma unroll
            for (int i2 = 0; i2 < 4; ++i2) {
                unsigned x0 = (i2 & 2) ? r0.y : r0.x;
                unsigned x1 = (i2 & 2) ? r1.y : r1.x;
                unsigned x2 = (i2 & 2) ? r2.y : r2.x;
                unsigned x3 = (i2 & 2) ? r3.y : r3.x;
                if (i2 & 1) { x0 >>= 16; x2 >>= 16; }
                else        { x0 &= 0xffffu; x2 &= 0xffffu; }
                unsigned px = (i2 & 1) ? (x0 | (x1 & 0xffff0000u))
                                       : (x0 | (x1 << 16));
                unsigned py = (i2 & 1) ? (x2 | (x3 & 0xffff0000u))
                                       : (x2 | (x3 << 16));
                int nloc = nq * 4 + i2;
                int sb = nloc * 128 + (((q >> 1) ^ ((nloc >> 2) & 7)) << 4) + ((q & 1) << 3);
                *(uint2*)((char*)Bl + sb) = make_uint2(px, py);
            }
        }
        // prefetch next K-step into regs (stays in flight across the barrier)
        if (kk < 3) {
#pragma unroll
            for (int i = 0; i < 4; ++i)
                areg[i] = *(const uint4*)(asrc[i] + (kk + 1) * 64);
#pragma unroll
            for (int i = 0; i < 2; ++i) {
#pragma unroll
                for (int r = 0; r < 4; ++r)
                    breg[i][r] = *(const uint2*)(bsrc[i] + (size_t)(kk + 1) * 64 * NPAD + r * NPAD);
                fl[i] = *(const float4*)(dwb_ + (kk + 1) * 64 + bq[i] * 4);
            }
        }
        asm volatile("s_waitcnt lgkmcnt(0)" ::: "memory");  // LDS writes visible; vmcnt NOT drained
        __builtin_amdgcn_s_barrier();
        __builtin_amdgcn_sched_barrier(0);
        // compute this K-step: 2 halves of K=32
#pragma unroll
        for (int h = 0; h < 2; ++h) {
            bf16x8 af[4], bfr[4];
            int cc = h * 4 + l4;
#pragma unroll
            for (int mf = 0; mf < 4; ++mf) {
                int m = wm + mf * 16 + l15;
                af[mf] = *(const bf16x8*)((const char*)Al + m * 128 + ((cc ^ (m & 7)) << 4));
            }
#pragma unroll
            for (int nf = 0; nf < 4; ++nf) {
                int n = wn + nf * 16 + l15;
                bfr[nf] = *(const bf16x8*)((const char*)Bl + n * 128 + ((cc ^ ((n >> 2) & 7)) << 4));
            }
#pragma unroll
            for (int mf = 0; mf < 4; ++mf)
#pragma unroll
                for (int nf = 0; nf < 4; ++nf)
                    acc[mf][nf] = __builtin_amdgcn_mfma_f32_16x16x32_bf16(
                        af[mf], bfr[nf], acc[mf][nf], 0, 0, 0);
        }
    }

    // epilogue: bias + relu + store + per-o-row plane max (atomic)
    float* zb = z + (size_t)b * COUT * HW;
#pragma unroll
    for (int mf = 0; mf < 4; ++mf) {
        int obase = m0 + wm + mf * 16 + l4 * 4;
        float bb0 = b2[obase + 0], bb1 = b2[obase + 1];
        float bb2v = b2[obase + 2], bb3 = b2[obase + 3];
        float rmax[4] = {0.f, 0.f, 0.f, 0.f};
#pragma unroll
        for (int nf = 0; nf < 4; ++nf) {
            int n = n0 + wn + nf * 16 + l15;
            bool valid = (n < HW);
            float v0 = fmaxf(acc[mf][nf][0] + bb0, 0.f);
            float v1 = fmaxf(acc[mf][nf][1] + bb1, 0.f);
            float v2 = fmaxf(acc[mf][nf][2] + bb2v, 0.f);
            float v3 = fmaxf(acc[mf][nf][3] + bb3, 0.f);
            if (valid) {
                zb[(size_t)(obase + 0) * HW + n] = v0;
                zb[(size_t)(obase + 1) * HW + n] = v1;
                zb[(size_t)(obase + 2) * HW + n] = v2;
                zb[(size_t)(obase + 3) * HW + n] = v3;
                rmax[0] = fmaxf(rmax[0], v0);
                rmax[1] = fmaxf(rmax[1], v1);
                rmax[2] = fmaxf(rmax[2], v2);
                rmax[3] = fmaxf(rmax[3], v3);
            }
        }
#pragma unroll
        for (int r = 0; r < 4; ++r) {
            float v = rmax[r];
            v = fmaxf(v, __shfl_xor(v, 1, 64));
            v = fmaxf(v, __shfl_xor(v, 2, 64));
            v = fmaxf(v, __shfl_xor(v, 4, 64));
            v = fmaxf(v, __shfl_xor(v, 8, 64));
            if (l15 == 0)
                atomicMax(&pwmax[b * COUT + obase + r], __float_as_uint(v));
        }
    }
}

// ---------------- K3: apply pointwise cut ---------------------------------
__global__ __launch_bounds__(256) void cut_kernel(const unsigned* __restrict__ pwmax,
                                                  float* __restrict__ z) {
    int base = blockIdx.x * 8;
#pragma unroll
    for (int j = 0; j < 8; ++j) {
        int bo = base + j;
        if (__uint_as_float(pwmax[bo]) >= 1e-3f) continue;
        float4* zp = (float4*)(z + (size_t)bo * HW);
        for (int i = threadIdx.x; i < HW / 4; i += 256)
            zp[i] = make_float4(0.f, 0.f, 0.f, 0.f);
    }
}

extern "C" void kernel_launch(void* const* d_in, const int* in_sizes, int n_in,
                              void* d_out, int out_size, void* d_ws, size_t ws_size,
                              hipStream_t stream) {
    const float* x   = (const float*)d_in[0];
    const float* dww = (const float*)d_in[1];
    const float* dwb = (const float*)d_in[2];
    const float* g1  = (const float*)d_in[3];
    const float* be1 = (const float*)d_in[4];
    const float* mu1 = (const float*)d_in[5];
    const float* va1 = (const float*)d_in[6];
    const float* pww = (const float*)d_in[7];
    const float* pwb = (const float*)d_in[8];
    const float* g2  = (const float*)d_in[9];
    const float* be2 = (const float*)d_in[10];
    const float* mu2 = (const float*)d_in[11];
    const float* va2 = (const float*)d_in[12];
    float* z = (float*)d_out;

    char* ws = (char*)d_ws;
    const size_t Y_BYTES = (size_t)BATCH * CIN * NPAD * 2;  // 52,428,800
    unsigned short* y  = (unsigned short*)ws;
    unsigned short* Wp = (unsigned short*)(ws + Y_BYTES);
    float* b2          = (float*)(ws + Y_BYTES + 131072);
    unsigned* pwmax    = (unsigned*)(ws + Y_BYTES + 131072 + 1024);
    float* dwmax       = (float*)(ws + Y_BYTES + 131072 + 1024 + 32768);

    prep_kernel<<<256, 256, 0, stream>>>(pww, pwb, g2, be2, mu2, va2, Wp, b2, pwmax);
    dw_kernel<<<1024, 256, 0, stream>>>(x, dww, dwb, g1, be1, mu1, va1, y, dwmax);
    pw_kernel<<<1600, 256, 0, stream>>>(y, Wp, b2, dwmax, z, pwmax);
    cut_kernel<<<BATCH * COUT / 8, 256, 0, stream>>>(pwmax, z);
}